// Round 2
// baseline (29409.174 us; speedup 1.0000x reference)
//
#include <hip/hip_runtime.h>
#include <cmath>

// Problem constants (from reference): B=256, T=256, D=128, E=32, F1=F2=512
#define B_   256
#define T_   256
#define D_   128
#define E_   32
#define F_   512
#define IN1  160            // D+E
#define CB   16             // blocks per cluster
#define RC   16             // rows per cluster
#define NCL  16             // clusters
#define PW   36             // LDS pitch for W1s/W2s rows
#define PW3  10             // LDS pitch for W3s rows
#define PA   20             // LDS pitch for act_t rows (16 rows + 4 pad)

#define ALPHA_F      0.1f
#define SCALE_F      0.31622776601683794f   // sqrt(0.1)

#define WS_SYNC_BYTES 4096
#define WS_NEED_BYTES (WS_SYNC_BYTES + (size_t)(NCL * F_ * RC) * 4u * 2u)  // h1t + h2t = 1 MiB

// ---------------- cluster barrier (hardened: all-thread fences) ----------------
__device__ __forceinline__ void cluster_barrier(unsigned* cnt, unsigned* gen, unsigned g) {
    __syncthreads();
    __threadfence();                       // ALL threads: release — own stores written back to coherent point
    if (threadIdx.x == 0) {
        unsigned a = __hip_atomic_fetch_add(cnt, 1u, __ATOMIC_RELAXED, __HIP_MEMORY_SCOPE_AGENT);
        if (a == CB - 1u) {
            __hip_atomic_store(cnt, 0u, __ATOMIC_RELAXED, __HIP_MEMORY_SCOPE_AGENT);
            __hip_atomic_store(gen, g, __ATOMIC_RELEASE, __HIP_MEMORY_SCOPE_AGENT);
        } else {
            while (__hip_atomic_load(gen, __ATOMIC_RELAXED, __HIP_MEMORY_SCOPE_AGENT) < g) {
                __builtin_amdgcn_s_sleep(2);
            }
        }
    }
    __syncthreads();
    __threadfence();                       // ALL threads: acquire — invalidate stale L1/L2 before reading peers' data
}

// ---------------- fused GEMM slice: out[16 x 32] = tanh(act^T @ Ws + b) ----------------
// act_t: LDS [K][PA] transposed activations (col r = batch row). Ws: LDS [K][PW].
// 8x8 per-thread tiles, 32-way K-split (k = kk*32 + ksg), LDS tree reduction into `red`
// (aliases act_t; act is dead after the MAC loop). Result -> gdst[c*16 + r] (transposed global).
template<int KK>
__device__ __forceinline__ void gemm_block(const float* act, const float* Ws, const float* bias,
                                           float* red, float* gdst, int tid) {
    const int tile = tid & 7;
    const int ksg  = tid >> 3;            // 0..31
    const int r0   = (tile & 1) * 8;
    const int c0   = (tile >> 1) * 8;

    float4 accA[8], accB[8];
    const float4 z4 = {0.f, 0.f, 0.f, 0.f};
#pragma unroll
    for (int i = 0; i < 8; i++) { accA[i] = z4; accB[i] = z4; }

    const float* ap = act + ksg * PA;
    const float* wp = Ws  + ksg * PW;
#pragma unroll
    for (int kk = 0; kk < KK; kk++) {
        float4 a0 = *(const float4*)(ap + r0);
        float4 a1 = *(const float4*)(ap + r0 + 4);
        float4 w0 = *(const float4*)(wp + c0);
        float4 w1 = *(const float4*)(wp + c0 + 4);
        float av[8] = {a0.x, a0.y, a0.z, a0.w, a1.x, a1.y, a1.z, a1.w};
#pragma unroll
        for (int ri = 0; ri < 8; ri++) {
            accA[ri].x += av[ri] * w0.x; accA[ri].y += av[ri] * w0.y;
            accA[ri].z += av[ri] * w0.z; accA[ri].w += av[ri] * w0.w;
            accB[ri].x += av[ri] * w1.x; accB[ri].y += av[ri] * w1.y;
            accB[ri].z += av[ri] * w1.z; accB[ri].w += av[ri] * w1.w;
        }
        ap += 32 * PA; wp += 32 * PW;
    }

    // tree reduction across ksg groups: 32 -> 2 (then combine sums the last 2)
    for (int half = 16; half >= 2; half >>= 1) {
        __syncthreads();
        if (ksg >= half && ksg < 2 * half) {
            float4* d4 = (float4*)(red + (((ksg - half) << 3) + tile) * 64);
#pragma unroll
            for (int i = 0; i < 8; i++) { d4[2 * i] = accA[i]; d4[2 * i + 1] = accB[i]; }
        }
        __syncthreads();
        if (ksg < half) {
            const float4* s4 = (const float4*)(red + ((ksg << 3) + tile) * 64);
#pragma unroll
            for (int i = 0; i < 8; i++) {
                float4 u = s4[2 * i], v = s4[2 * i + 1];
                accA[i].x += u.x; accA[i].y += u.y; accA[i].z += u.z; accA[i].w += u.w;
                accB[i].x += v.x; accB[i].y += v.y; accB[i].z += v.z; accB[i].w += v.w;
            }
        }
    }
    __syncthreads();
    if (ksg < 2) {
        float4* d4 = (float4*)(red + ((ksg << 3) + tile) * 64);
#pragma unroll
        for (int i = 0; i < 8; i++) { d4[2 * i] = accA[i]; d4[2 * i + 1] = accB[i]; }
    }
    __syncthreads();
    // combine: 2 outputs per thread (rows r, r+1 of col c), o = c*16 + r (r even)
    {
        int o = tid << 1;
        int c = o >> 4, r = o & 15;
        int tl = ((c >> 3) << 1) | (r >> 3);
        int i0 = (r & 7) * 8 + (c & 7);
        float v0 = red[tl * 64 + i0]     + red[(8 + tl) * 64 + i0]     + bias[c];
        float v1 = red[tl * 64 + i0 + 8] + red[(8 + tl) * 64 + i0 + 8] + bias[c];
        float2 res = {tanhf(v0), tanhf(v1)};
        *(float2*)(gdst + c * 16 + r) = res;
    }
}

__global__ void __launch_bounds__(256)
sde_scan_kernel(const float* __restrict__ carry, const float* __restrict__ x,
                const float* __restrict__ ext,   const float* __restrict__ noise,
                const float* __restrict__ W1,    const float* __restrict__ b1,
                const float* __restrict__ W2,    const float* __restrict__ b2,
                const float* __restrict__ W3,    const float* __restrict__ b3,
                float* __restrict__ out,         void* __restrict__ ws) {
    __shared__ alignas(16) float W1s[IN1 * PW];    // 23,040 B
    __shared__ alignas(16) float W2s[F_ * PW];     // 73,728 B
    __shared__ alignas(16) float W3s[F_ * PW3];    // 20,480 B
    __shared__ alignas(16) float act_t[F_ * PA];   // 40,960 B (z / h1 / h2 staging + reduction alias)
    __shared__ alignas(16) float b1s[32], b2s[32], b3s[8];

    const int tid = threadIdx.x;
    const int bid = blockIdx.x;
    const int cl  = bid & 15;            // cluster
    const int j   = bid >> 4;            // block-in-cluster 0..15
    const int rb  = cl * RC;             // global row base
    const int cb  = j * 32;              // F1/F2 col base
    const int c3b = j * 8;               // D col base

    unsigned* syncb = (unsigned*)ws;
    unsigned* cnt = syncb + cl * 64;           // 256B stride per cluster
    unsigned* gen = syncb + cl * 64 + 16;
    float* h1t = (float*)((char*)ws + WS_SYNC_BYTES);  // [NCL][512][16]
    float* h2t = h1t + NCL * F_ * RC;                  // [NCL][512][16]
    float* h1l = h1t + cl * (F_ * RC);
    float* h2l = h2t + cl * (F_ * RC);

    float* yfin  = out;
    float* ys_o  = out + B_ * D_;
    float* mup_o = ys_o  + (size_t)B_ * T_ * D_;
    float* mus_o = mup_o + (size_t)B_ * T_ * D_;
    float* std_o = mus_o + (size_t)B_ * T_ * D_;

    // ---- load weight slices to LDS (once) ----
    for (int e = tid; e < IN1 * 32; e += 256) { int k = e >> 5, c = e & 31; W1s[k * PW + c] = W1[k * F_ + cb + c]; }
    for (int e = tid; e < F_ * 32; e += 256)  { int k = e >> 5, c = e & 31; W2s[k * PW + c] = W2[k * F_ + cb + c]; }
    for (int e = tid; e < F_ * 8; e += 256)   { int k = e >> 3, c = e & 7;  W3s[k * PW3 + c] = W3[k * D_ + c3b + c]; }
    if (tid < 32) { b1s[tid] = b1[cb + tid]; b2s[tid] = b2[cb + tid]; }
    if (tid < 8)  { b3s[tid] = b3[c3b + tid]; }

    const int tile = tid & 7;
    const int ksg  = tid >> 3;
    const int r0   = (tile & 1) * 8;

    unsigned g = 0;
    for (int t = 0; t < T_; t++) {
        // ---- stage Z: act_t[k][r] = concat(y_{t-1}, u_t) transposed ----
        if (t == 0) {
            for (int e = tid; e < D_ * RC; e += 256) {
                int k = e >> 4, r = e & 15;
                act_t[k * PA + r] = carry[(rb + r) * D_ + k];
            }
        } else {
            for (int e = tid; e < D_ * RC; e += 256) {
                int k = e >> 4, r = e & 15;
                act_t[k * PA + r] = ys_o[((size_t)(rb + r) * T_ + (t - 1)) * D_ + k];
            }
        }
        for (int e = tid; e < E_ * RC; e += 256) {
            int u = e >> 4, r = e & 15;
            act_t[(D_ + u) * PA + r] = ext[((size_t)(rb + r) * T_ + t) * E_ + u];
        }
        __syncthreads();

        // ---- stage 1: h1 slice ----
        gemm_block<5>(act_t, W1s, b1s, act_t, h1l + cb * 16, tid);
        cluster_barrier(cnt, gen, ++g);

        // ---- restage full h1 (transposed, coalesced) ----
#pragma unroll
        for (int i = 0; i < 8; i++) {
            int e4 = tid * 4 + i * 1024;
            float4 v = *(const float4*)(h1l + e4);
            *(float4*)(act_t + (e4 >> 4) * PA + (e4 & 15)) = v;
        }
        __syncthreads();

        // ---- stage 2: h2 slice ----
        gemm_block<16>(act_t, W2s, b2s, act_t, h2l + cb * 16, tid);
        cluster_barrier(cnt, gen, ++g);

        // ---- restage full h2 ----
#pragma unroll
        for (int i = 0; i < 8; i++) {
            int e4 = tid * 4 + i * 1024;
            float4 v = *(const float4*)(h2l + e4);
            *(float4*)(act_t + (e4 >> 4) * PA + (e4 & 15)) = v;
        }
        __syncthreads();

        // ---- stage 3: mu_phi slice [16 x 8] + pointwise ----
        {
            float2 acc2[8];
#pragma unroll
            for (int i = 0; i < 8; i++) acc2[i] = float2{0.f, 0.f};
            const float* ap = act_t + ksg * PA;
            const float* wp = W3s + ksg * PW3 + (tile >> 1) * 2;
#pragma unroll
            for (int kk = 0; kk < 16; kk++) {
                float4 a0 = *(const float4*)(ap + r0);
                float4 a1 = *(const float4*)(ap + r0 + 4);
                float2 w  = *(const float2*)wp;
                float av[8] = {a0.x, a0.y, a0.z, a0.w, a1.x, a1.y, a1.z, a1.w};
#pragma unroll
                for (int ri = 0; ri < 8; ri++) {
                    acc2[ri].x += av[ri] * w.x;
                    acc2[ri].y += av[ri] * w.y;
                }
                ap += 32 * PA; wp += 32 * PW3;
            }
            float* red = act_t;
            for (int half = 16; half >= 2; half >>= 1) {
                __syncthreads();
                if (ksg >= half && ksg < 2 * half) {
                    float2* d2 = (float2*)(red + (((ksg - half) << 3) + tile) * 16);
#pragma unroll
                    for (int i = 0; i < 8; i++) d2[i] = acc2[i];
                }
                __syncthreads();
                if (ksg < half) {
                    const float2* s2 = (const float2*)(red + ((ksg << 3) + tile) * 16);
#pragma unroll
                    for (int i = 0; i < 8; i++) { float2 u = s2[i]; acc2[i].x += u.x; acc2[i].y += u.y; }
                }
            }
            __syncthreads();
            if (ksg < 2) {
                float2* d2 = (float2*)(red + ((ksg << 3) + tile) * 16);
#pragma unroll
                for (int i = 0; i < 8; i++) d2[i] = acc2[i];
            }
            __syncthreads();
            if (tid < 128) {
                int o = tid;
                int r = o >> 3, c = o & 7;
                int tl  = ((c >> 1) << 1) | (r >> 3);
                int idx = (r & 7) * 2 + (c & 1);
                float mu_phi = red[tl * 16 + idx] + red[(8 + tl) * 16 + idx] + b3s[c];
                int rg = rb + r;
                int cg = c3b + c;
                size_t bt = (size_t)rg * T_ + t;
                float yv = (t == 0) ? carry[rg * D_ + cg]
                                    : ys_o[((size_t)rg * T_ + (t - 1)) * D_ + cg];
                float x1 = x[bt * (2 * D_) + cg];
                float x2 = x[bt * (2 * D_) + D_ + cg];
                float nv = noise[bt * D_ + cg];
                float mu = (1.0f - ALPHA_F) * yv + ALPHA_F * mu_phi + x1;
                float sp = (x2 > 0.f) ? (x2 + log1pf(expf(-x2))) : log1pf(expf(x2));
                float sd = SCALE_F * sp;
                float yn = mu + sd * nv;
                mup_o[bt * D_ + cg] = mu_phi;
                mus_o[bt * D_ + cg] = mu;
                std_o[bt * D_ + cg] = sd;
                ys_o [bt * D_ + cg] = yn;
                if (t == T_ - 1) yfin[rg * D_ + cg] = yn;
            }
        }
        cluster_barrier(cnt, gen, ++g);
    }
}

extern "C" void kernel_launch(void* const* d_in, const int* in_sizes, int n_in,
                              void* d_out, int out_size, void* d_ws, size_t ws_size,
                              hipStream_t stream) {
    const float* carry = (const float*)d_in[0];
    const float* x     = (const float*)d_in[1];
    const float* ext   = (const float*)d_in[2];
    const float* noise = (const float*)d_in[3];
    const float* W1    = (const float*)d_in[4];
    const float* b1    = (const float*)d_in[5];
    const float* W2    = (const float*)d_in[6];
    const float* b2    = (const float*)d_in[7];
    const float* W3    = (const float*)d_in[8];
    const float* b3    = (const float*)d_in[9];
    float* out = (float*)d_out;
    void* ws   = d_ws;

    // Zero the ENTIRE used ws region each call: sync state must start at 0, and
    // zero-filled exchange buffers turn any residual stale-read into a small,
    // diagnosable error instead of arbitrary garbage.
    hipMemsetAsync(d_ws, 0, WS_NEED_BYTES, stream);

    // Plain launch: grid = 256 = CU count, 1 block/CU by LDS usage -> co-resident.
    sde_scan_kernel<<<dim3(256), dim3(256), 0, stream>>>(
        carry, x, ext, noise, W1, b1, W2, b2, W3, b3, out, ws);
}

// Round 3
// 5546.687 us; speedup vs baseline: 5.3021x; 5.3021x over previous
//
#include <hip/hip_runtime.h>
#include <cmath>

// Problem constants (from reference): B=256, T=256, D=128, E=32, F1=F2=512
#define B_   256
#define T_   256
#define D_   128
#define E_   32
#define F_   512
#define IN1  160            // D+E
#define CB   16             // blocks per cluster
#define RC   16             // rows per cluster
#define NCL  16             // clusters
#define PW   36             // LDS pitch for W1s/W2s rows
#define PW3  10             // LDS pitch for W3s rows
#define PA   20             // LDS pitch for act_t rows (16 rows + 4 pad)

#define ALPHA_F      0.1f
#define SCALE_F      0.31622776601683794f   // sqrt(0.1)

#define WS_SYNC_BYTES 4096

// ---------------- coherent-point exchange primitives ----------------
// Agent-scope relaxed atomics lower to global_load/store with sc0 sc1:
// stores write through to the device coherent point, loads bypass stale
// local L1/L2. This replaces __threadfence()'s buffer_wbl2/buffer_inv
// cache walks (the 28ms cost in R2) with zero per-barrier cache ops.
__device__ __forceinline__ void st_coh2(float* p, float2 v) {
    union { float2 f; unsigned long long u; } c; c.f = v;
    __hip_atomic_store((unsigned long long*)p, c.u, __ATOMIC_RELAXED, __HIP_MEMORY_SCOPE_AGENT);
}
__device__ __forceinline__ float2 ld_coh2(const float* p) {
    union { float2 f; unsigned long long u; } c;
    c.u = __hip_atomic_load((const unsigned long long*)p, __ATOMIC_RELAXED, __HIP_MEMORY_SCOPE_AGENT);
    return c.f;
}
__device__ __forceinline__ void st_coh1(float* p, float v) {
    union { float f; unsigned u; } c; c.f = v;
    __hip_atomic_store((unsigned*)p, c.u, __ATOMIC_RELAXED, __HIP_MEMORY_SCOPE_AGENT);
}

// ---------------- cluster barrier (no cache-walk fences) ----------------
// Monotonic arrival counter (never reset -> no reset/gen reorder race).
// Correctness: each wave drains its own write-through stores (vmcnt(0))
// before s_barrier; the arrival atomic is issued after -> all exchange
// data is at the coherent point before gen advances; readers use sc1
// loads which cannot hit stale cache lines.
__device__ __forceinline__ void cluster_barrier(unsigned* cnt, unsigned* gen, unsigned g) {
    asm volatile("s_waitcnt vmcnt(0)" ::: "memory");
    __syncthreads();
    if (threadIdx.x == 0) {
        unsigned a = __hip_atomic_fetch_add(cnt, 1u, __ATOMIC_RELAXED, __HIP_MEMORY_SCOPE_AGENT);
        if (a == g * CB - 1u) {
            __hip_atomic_store(gen, g, __ATOMIC_RELAXED, __HIP_MEMORY_SCOPE_AGENT);
        } else {
            while (__hip_atomic_load(gen, __ATOMIC_RELAXED, __HIP_MEMORY_SCOPE_AGENT) < g) {
                __builtin_amdgcn_s_sleep(1);
            }
        }
    }
    __syncthreads();
}

// ---------------- fused GEMM slice: out[16 x 32] = tanh(act^T @ Ws + b) ----------------
// act_t: LDS [K][PA] transposed activations (col r = batch row). Ws: LDS [K][PW].
// 8x8 per-thread tiles, 32-way K-split (k = kk*32 + ksg), LDS tree reduction into `red`
// (aliases act_t; act is dead after the MAC loop). Result -> gdst[c*16 + r] (transposed,
// coherent-point store).
template<int KK>
__device__ __forceinline__ void gemm_block(const float* act, const float* Ws, const float* bias,
                                           float* red, float* gdst, int tid) {
    const int tile = tid & 7;
    const int ksg  = tid >> 3;            // 0..31
    const int r0   = (tile & 1) * 8;
    const int c0   = (tile >> 1) * 8;

    float4 accA[8], accB[8];
    const float4 z4 = {0.f, 0.f, 0.f, 0.f};
#pragma unroll
    for (int i = 0; i < 8; i++) { accA[i] = z4; accB[i] = z4; }

    const float* ap = act + ksg * PA;
    const float* wp = Ws  + ksg * PW;
#pragma unroll
    for (int kk = 0; kk < KK; kk++) {
        float4 a0 = *(const float4*)(ap + r0);
        float4 a1 = *(const float4*)(ap + r0 + 4);
        float4 w0 = *(const float4*)(wp + c0);
        float4 w1 = *(const float4*)(wp + c0 + 4);
        float av[8] = {a0.x, a0.y, a0.z, a0.w, a1.x, a1.y, a1.z, a1.w};
#pragma unroll
        for (int ri = 0; ri < 8; ri++) {
            accA[ri].x += av[ri] * w0.x; accA[ri].y += av[ri] * w0.y;
            accA[ri].z += av[ri] * w0.z; accA[ri].w += av[ri] * w0.w;
            accB[ri].x += av[ri] * w1.x; accB[ri].y += av[ri] * w1.y;
            accB[ri].z += av[ri] * w1.z; accB[ri].w += av[ri] * w1.w;
        }
        ap += 32 * PA; wp += 32 * PW;
    }

    // tree reduction across ksg groups: 32 -> 2 (then combine sums the last 2)
    for (int half = 16; half >= 2; half >>= 1) {
        __syncthreads();
        if (ksg >= half && ksg < 2 * half) {
            float4* d4 = (float4*)(red + (((ksg - half) << 3) + tile) * 64);
#pragma unroll
            for (int i = 0; i < 8; i++) { d4[2 * i] = accA[i]; d4[2 * i + 1] = accB[i]; }
        }
        __syncthreads();
        if (ksg < half) {
            const float4* s4 = (const float4*)(red + ((ksg << 3) + tile) * 64);
#pragma unroll
            for (int i = 0; i < 8; i++) {
                float4 u = s4[2 * i], v = s4[2 * i + 1];
                accA[i].x += u.x; accA[i].y += u.y; accA[i].z += u.z; accA[i].w += u.w;
                accB[i].x += v.x; accB[i].y += v.y; accB[i].z += v.z; accB[i].w += v.w;
            }
        }
    }
    __syncthreads();
    if (ksg < 2) {
        float4* d4 = (float4*)(red + ((ksg << 3) + tile) * 64);
#pragma unroll
        for (int i = 0; i < 8; i++) { d4[2 * i] = accA[i]; d4[2 * i + 1] = accB[i]; }
    }
    __syncthreads();
    // combine: 2 outputs per thread (rows r, r+1 of col c), o = c*16 + r (r even)
    {
        int o = tid << 1;
        int c = o >> 4, r = o & 15;
        int tl = ((c >> 3) << 1) | (r >> 3);
        int i0 = (r & 7) * 8 + (c & 7);
        float v0 = red[tl * 64 + i0]     + red[(8 + tl) * 64 + i0]     + bias[c];
        float v1 = red[tl * 64 + i0 + 8] + red[(8 + tl) * 64 + i0 + 8] + bias[c];
        float2 res = {tanhf(v0), tanhf(v1)};
        st_coh2(gdst + c * 16 + r, res);
    }
}

__global__ void __launch_bounds__(256)
sde_scan_kernel(const float* __restrict__ carry, const float* __restrict__ x,
                const float* __restrict__ ext,   const float* __restrict__ noise,
                const float* __restrict__ W1,    const float* __restrict__ b1,
                const float* __restrict__ W2,    const float* __restrict__ b2,
                const float* __restrict__ W3,    const float* __restrict__ b3,
                float* __restrict__ out,         void* __restrict__ ws) {
    __shared__ alignas(16) float W1s[IN1 * PW];    // 23,040 B
    __shared__ alignas(16) float W2s[F_ * PW];     // 73,728 B
    __shared__ alignas(16) float W3s[F_ * PW3];    // 20,480 B
    __shared__ alignas(16) float act_t[F_ * PA];   // 40,960 B (z / h1 / h2 staging + reduction alias)
    __shared__ alignas(16) float b1s[32], b2s[32], b3s[8];

    const int tid = threadIdx.x;
    const int bid = blockIdx.x;
    const int cl  = bid & 15;            // cluster
    const int j   = bid >> 4;            // block-in-cluster 0..15
    const int rb  = cl * RC;             // global row base
    const int cb  = j * 32;              // F1/F2 col base
    const int c3b = j * 8;               // D col base

    unsigned* syncb = (unsigned*)ws;
    unsigned* cnt = syncb + cl * 64;           // 256B stride per cluster
    unsigned* gen = syncb + cl * 64 + 16;
    float* y_gt = (float*)((char*)ws + WS_SYNC_BYTES);  // [NCL][128][16] y exchange (transposed)
    float* h1t  = y_gt + NCL * D_ * RC;                 // [NCL][512][16]
    float* h2t  = h1t + NCL * F_ * RC;                  // [NCL][512][16]
    float* ygl = y_gt + cl * (D_ * RC);
    float* h1l = h1t + cl * (F_ * RC);
    float* h2l = h2t + cl * (F_ * RC);

    float* yfin  = out;
    float* ys_o  = out + B_ * D_;
    float* mup_o = ys_o  + (size_t)B_ * T_ * D_;
    float* mus_o = mup_o + (size_t)B_ * T_ * D_;
    float* std_o = mus_o + (size_t)B_ * T_ * D_;

    // ---- load weight slices to LDS (once) ----
    for (int e = tid; e < IN1 * 32; e += 256) { int k = e >> 5, c = e & 31; W1s[k * PW + c] = W1[k * F_ + cb + c]; }
    for (int e = tid; e < F_ * 32; e += 256)  { int k = e >> 5, c = e & 31; W2s[k * PW + c] = W2[k * F_ + cb + c]; }
    for (int e = tid; e < F_ * 8; e += 256)   { int k = e >> 3, c = e & 7;  W3s[k * PW3 + c] = W3[k * D_ + c3b + c]; }
    if (tid < 32) { b1s[tid] = b1[cb + tid]; b2s[tid] = b2[cb + tid]; }
    if (tid < 8)  { b3s[tid] = b3[c3b + tid]; }

    const int tile = tid & 7;
    const int ksg  = tid >> 3;
    const int r0   = (tile & 1) * 8;

    // pointwise thread's carried state: same (r,c) element every step
    float y_reg = 0.f;
    if (tid < 128) {
        int r = tid >> 3, c = tid & 7;
        y_reg = carry[(rb + r) * D_ + (c3b + c)];
    }

    unsigned g = 0;
    for (int t = 0; t < T_; t++) {
        // ---- stage Z: act_t[k][r] = concat(y_{t-1}, u_t) transposed ----
        if (t == 0) {
            for (int e = tid; e < D_ * RC; e += 256) {
                int k = e >> 4, r = e & 15;
                act_t[k * PA + r] = carry[(rb + r) * D_ + k];
            }
        } else {
            // y exchange buffer is already transposed [k][r]; coherent-point pair loads
#pragma unroll
            for (int i = 0; i < 4; i++) {
                int e2 = tid * 2 + i * 512;
                int k = e2 >> 4, r = e2 & 15;
                float2 v = ld_coh2(ygl + e2);
                *(float2*)(act_t + k * PA + r) = v;
            }
        }
        for (int e = tid; e < E_ * RC; e += 256) {
            int u = e >> 4, r = e & 15;
            act_t[(D_ + u) * PA + r] = ext[((size_t)(rb + r) * T_ + t) * E_ + u];
        }
        __syncthreads();

        // ---- stage 1: h1 slice ----
        gemm_block<5>(act_t, W1s, b1s, act_t, h1l + cb * 16, tid);
        cluster_barrier(cnt, gen, ++g);

        // ---- restage full h1 (transposed, coherent-point loads) ----
#pragma unroll
        for (int i = 0; i < 8; i++) {
            int e4 = tid * 4 + i * 1024;
            float2 v0 = ld_coh2(h1l + e4);
            float2 v1 = ld_coh2(h1l + e4 + 2);
            int k = e4 >> 4, r = e4 & 15;
            *(float2*)(act_t + k * PA + r)     = v0;
            *(float2*)(act_t + k * PA + r + 2) = v1;
        }
        __syncthreads();

        // ---- stage 2: h2 slice ----
        gemm_block<16>(act_t, W2s, b2s, act_t, h2l + cb * 16, tid);
        cluster_barrier(cnt, gen, ++g);

        // ---- restage full h2 ----
#pragma unroll
        for (int i = 0; i < 8; i++) {
            int e4 = tid * 4 + i * 1024;
            float2 v0 = ld_coh2(h2l + e4);
            float2 v1 = ld_coh2(h2l + e4 + 2);
            int k = e4 >> 4, r = e4 & 15;
            *(float2*)(act_t + k * PA + r)     = v0;
            *(float2*)(act_t + k * PA + r + 2) = v1;
        }
        __syncthreads();

        // ---- stage 3: mu_phi slice [16 x 8] + pointwise ----
        {
            float2 acc2[8];
#pragma unroll
            for (int i = 0; i < 8; i++) acc2[i] = float2{0.f, 0.f};
            const float* ap = act_t + ksg * PA;
            const float* wp = W3s + ksg * PW3 + (tile >> 1) * 2;
#pragma unroll
            for (int kk = 0; kk < 16; kk++) {
                float4 a0 = *(const float4*)(ap + r0);
                float4 a1 = *(const float4*)(ap + r0 + 4);
                float2 w  = *(const float2*)wp;
                float av[8] = {a0.x, a0.y, a0.z, a0.w, a1.x, a1.y, a1.z, a1.w};
#pragma unroll
                for (int ri = 0; ri < 8; ri++) {
                    acc2[ri].x += av[ri] * w.x;
                    acc2[ri].y += av[ri] * w.y;
                }
                ap += 32 * PA; wp += 32 * PW3;
            }
            float* red = act_t;
            for (int half = 16; half >= 2; half >>= 1) {
                __syncthreads();
                if (ksg >= half && ksg < 2 * half) {
                    float2* d2 = (float2*)(red + (((ksg - half) << 3) + tile) * 16);
#pragma unroll
                    for (int i = 0; i < 8; i++) d2[i] = acc2[i];
                }
                __syncthreads();
                if (ksg < half) {
                    const float2* s2 = (const float2*)(red + ((ksg << 3) + tile) * 16);
#pragma unroll
                    for (int i = 0; i < 8; i++) { float2 u = s2[i]; acc2[i].x += u.x; acc2[i].y += u.y; }
                }
            }
            __syncthreads();
            if (ksg < 2) {
                float2* d2 = (float2*)(red + ((ksg << 3) + tile) * 16);
#pragma unroll
                for (int i = 0; i < 8; i++) d2[i] = acc2[i];
            }
            __syncthreads();
            if (tid < 128) {
                int o = tid;
                int r = o >> 3, c = o & 7;
                int tl  = ((c >> 1) << 1) | (r >> 3);
                int idx = (r & 7) * 2 + (c & 1);
                float mu_phi = red[tl * 16 + idx] + red[(8 + tl) * 16 + idx] + b3s[c];
                int rg = rb + r;
                int cg = c3b + c;
                size_t bt = (size_t)rg * T_ + t;
                float yv = y_reg;
                float x1 = x[bt * (2 * D_) + cg];
                float x2 = x[bt * (2 * D_) + D_ + cg];
                float nv = noise[bt * D_ + cg];
                float mu = (1.0f - ALPHA_F) * yv + ALPHA_F * mu_phi + x1;
                float sp = (x2 > 0.f) ? (x2 + log1pf(expf(-x2))) : log1pf(expf(x2));
                float sd = SCALE_F * sp;
                float yn = mu + sd * nv;
                mup_o[bt * D_ + cg] = mu_phi;
                mus_o[bt * D_ + cg] = mu;
                std_o[bt * D_ + cg] = sd;
                ys_o [bt * D_ + cg] = yn;
                st_coh1(ygl + cg * 16 + r, yn);    // y exchange for next step's staging
                y_reg = yn;
                if (t == T_ - 1) yfin[rg * D_ + cg] = yn;
            }
        }
        cluster_barrier(cnt, gen, ++g);
    }
}

extern "C" void kernel_launch(void* const* d_in, const int* in_sizes, int n_in,
                              void* d_out, int out_size, void* d_ws, size_t ws_size,
                              hipStream_t stream) {
    const float* carry = (const float*)d_in[0];
    const float* x     = (const float*)d_in[1];
    const float* ext   = (const float*)d_in[2];
    const float* noise = (const float*)d_in[3];
    const float* W1    = (const float*)d_in[4];
    const float* b1    = (const float*)d_in[5];
    const float* W2    = (const float*)d_in[6];
    const float* b2    = (const float*)d_in[7];
    const float* W3    = (const float*)d_in[8];
    const float* b3    = (const float*)d_in[9];
    float* out = (float*)d_out;
    void* ws   = d_ws;

    // Only the sync counters need zeroing (exchange buffers are written-before-read).
    hipMemsetAsync(d_ws, 0, WS_SYNC_BYTES, stream);

    // Plain launch: grid = 256 = CU count, 1 block/CU by LDS usage -> co-resident.
    sde_scan_kernel<<<dim3(256), dim3(256), 0, stream>>>(
        carry, x, ext, noise, W1, b1, W2, b2, W3, b3, out, ws);
}

// Round 4
// 4323.599 us; speedup vs baseline: 6.8020x; 1.2829x over previous
//
#include <hip/hip_runtime.h>
#include <cmath>

// Problem constants (from reference): B=256, T=256, D=128, E=32, F1=F2=512
#define B_   256
#define T_   256
#define D_   128
#define E_   32
#define F_   512
#define IN1  160            // D+E
#define CB   16             // blocks per cluster
#define RC   16             // rows per cluster
#define NCL  16             // clusters
#define PW   36             // LDS pitch for W1s/W2s rows (stride-4-banks: conflict-free per quarter-wave)
#define PW3  10             // LDS pitch for W3s rows
#define PA   20             // LDS pitch for act_t rows (16 rows + 4 pad)
#define RST  68             // reduction tile stride, floats (was 64: bank-0-aligned = 16-way conflict!)
#define RST3 18             // stage-3 reduction stride, floats (was 16: 8-way conflict)

#define ALPHA_F      0.1f
#define SCALE_F      0.31622776601683794f   // sqrt(0.1)

#define WS_SYNC_BYTES 4096

// ---------------- coherent-point exchange primitives ----------------
// Agent-scope relaxed atomics lower to global_load/store with sc0 sc1:
// stores write through to the device coherent point, loads bypass stale
// local L1/L2. No buffer_wbl2/buffer_inv cache walks (the 28ms cost in R2).
__device__ __forceinline__ void st_coh2(float* p, float2 v) {
    union { float2 f; unsigned long long u; } c; c.f = v;
    __hip_atomic_store((unsigned long long*)p, c.u, __ATOMIC_RELAXED, __HIP_MEMORY_SCOPE_AGENT);
}
__device__ __forceinline__ float2 ld_coh2(const float* p) {
    union { float2 f; unsigned long long u; } c;
    c.u = __hip_atomic_load((const unsigned long long*)p, __ATOMIC_RELAXED, __HIP_MEMORY_SCOPE_AGENT);
    return c.f;
}
__device__ __forceinline__ void st_coh1(float* p, float v) {
    union { float f; unsigned u; } c; c.f = v;
    __hip_atomic_store((unsigned*)p, c.u, __ATOMIC_RELAXED, __HIP_MEMORY_SCOPE_AGENT);
}

// ---------------- cluster barrier (no cache-walk fences) ----------------
// Monotonic arrival counter (never reset -> no reset/gen reorder race).
// Each wave drains its write-through stores (vmcnt(0)) before s_barrier;
// arrival atomic issued after -> exchange data is at the coherent point
// before gen advances; readers' sc1 loads cannot hit stale cache lines.
__device__ __forceinline__ void cluster_barrier(unsigned* cnt, unsigned* gen, unsigned g) {
    asm volatile("s_waitcnt vmcnt(0)" ::: "memory");
    __syncthreads();
    if (threadIdx.x == 0) {
        unsigned a = __hip_atomic_fetch_add(cnt, 1u, __ATOMIC_RELAXED, __HIP_MEMORY_SCOPE_AGENT);
        if (a == g * CB - 1u) {
            __hip_atomic_store(gen, g, __ATOMIC_RELAXED, __HIP_MEMORY_SCOPE_AGENT);
        } else {
            while (__hip_atomic_load(gen, __ATOMIC_RELAXED, __HIP_MEMORY_SCOPE_AGENT) < g) {
                __builtin_amdgcn_s_sleep(1);
            }
        }
    }
    __syncthreads();
}

// ---------------- fused GEMM slice: out[16 x 32] = tanh(act^T @ Ws + b) ----------------
// act_t: LDS [K][PA] transposed activations (col r = batch row). Ws: LDS [K][PW].
// 8x8 per-thread tiles, 32-way K-split (k = kk*32 + ksg), LDS tree reduction into `red`
// (aliases act_t; act is dead after the MAC loop). Partial tiles stored at stride RST=68
// floats (4-bank skew per idx -> 2 touches/bank per quarter-wave = LDS floor).
template<int KK>
__device__ __forceinline__ void gemm_block(const float* act, const float* Ws, const float* bias,
                                           float* red, float* gdst, int tid) {
    const int tile = tid & 7;
    const int ksg  = tid >> 3;            // 0..31
    const int r0   = (tile & 1) * 8;
    const int c0   = (tile >> 1) * 8;

    float4 accA[8], accB[8];
    const float4 z4 = {0.f, 0.f, 0.f, 0.f};
#pragma unroll
    for (int i = 0; i < 8; i++) { accA[i] = z4; accB[i] = z4; }

    const float* ap = act + ksg * PA;
    const float* wp = Ws  + ksg * PW;
#pragma unroll
    for (int kk = 0; kk < KK; kk++) {
        float4 a0 = *(const float4*)(ap + r0);
        float4 a1 = *(const float4*)(ap + r0 + 4);
        float4 w0 = *(const float4*)(wp + c0);
        float4 w1 = *(const float4*)(wp + c0 + 4);
        float av[8] = {a0.x, a0.y, a0.z, a0.w, a1.x, a1.y, a1.z, a1.w};
#pragma unroll
        for (int ri = 0; ri < 8; ri++) {
            accA[ri].x += av[ri] * w0.x; accA[ri].y += av[ri] * w0.y;
            accA[ri].z += av[ri] * w0.z; accA[ri].w += av[ri] * w0.w;
            accB[ri].x += av[ri] * w1.x; accB[ri].y += av[ri] * w1.y;
            accB[ri].z += av[ri] * w1.z; accB[ri].w += av[ri] * w1.w;
        }
        ap += 32 * PA; wp += 32 * PW;
    }

    // tree reduction across ksg groups: 32 -> 2 (then combine sums the last 2)
    for (int half = 16; half >= 2; half >>= 1) {
        __syncthreads();
        if (ksg >= half && ksg < 2 * half) {
            float4* d4 = (float4*)(red + (((ksg - half) << 3) + tile) * RST);
#pragma unroll
            for (int i = 0; i < 8; i++) { d4[2 * i] = accA[i]; d4[2 * i + 1] = accB[i]; }
        }
        __syncthreads();
        if (ksg < half) {
            const float4* s4 = (const float4*)(red + ((ksg << 3) + tile) * RST);
#pragma unroll
            for (int i = 0; i < 8; i++) {
                float4 u = s4[2 * i], v = s4[2 * i + 1];
                accA[i].x += u.x; accA[i].y += u.y; accA[i].z += u.z; accA[i].w += u.w;
                accB[i].x += v.x; accB[i].y += v.y; accB[i].z += v.z; accB[i].w += v.w;
            }
        }
    }
    __syncthreads();
    if (ksg < 2) {
        float4* d4 = (float4*)(red + ((ksg << 3) + tile) * RST);
#pragma unroll
        for (int i = 0; i < 8; i++) { d4[2 * i] = accA[i]; d4[2 * i + 1] = accB[i]; }
    }
    __syncthreads();
    // combine: 2 outputs per thread (rows r, r+1 of col c), o = c*16 + r (r even)
    {
        int o = tid << 1;
        int c = o >> 4, r = o & 15;
        int tl = ((c >> 3) << 1) | (r >> 3);
        int i0 = (r & 7) * 8 + (c & 7);
        float v0 = red[tl * RST + i0]     + red[(8 + tl) * RST + i0]     + bias[c];
        float v1 = red[tl * RST + i0 + 8] + red[(8 + tl) * RST + i0 + 8] + bias[c];
        float2 res = {tanhf(v0), tanhf(v1)};
        st_coh2(gdst + c * 16 + r, res);
    }
}

__global__ void __launch_bounds__(256)
sde_scan_kernel(const float* __restrict__ carry, const float* __restrict__ x,
                const float* __restrict__ ext,   const float* __restrict__ noise,
                const float* __restrict__ W1,    const float* __restrict__ b1,
                const float* __restrict__ W2,    const float* __restrict__ b2,
                const float* __restrict__ W3,    const float* __restrict__ b3,
                float* __restrict__ out,         void* __restrict__ ws) {
    __shared__ alignas(16) float W1s[IN1 * PW];    // 23,040 B
    __shared__ alignas(16) float W2s[F_ * PW];     // 73,728 B
    __shared__ alignas(16) float W3s[F_ * PW3];    // 20,480 B
    __shared__ alignas(16) float act_t[F_ * PA];   // 40,960 B (z / h1 / h2 staging + reduction alias)
    __shared__ alignas(16) float b1s[32], b2s[32], b3s[8];

    const int tid = threadIdx.x;
    const int bid = blockIdx.x;
    const int cl  = bid & 15;            // cluster
    const int j   = bid >> 4;            // block-in-cluster 0..15
    const int rb  = cl * RC;             // global row base
    const int cb  = j * 32;              // F1/F2 col base
    const int c3b = j * 8;               // D col base

    unsigned* syncb = (unsigned*)ws;
    unsigned* cnt = syncb + cl * 64;           // 256B stride per cluster
    unsigned* gen = syncb + cl * 64 + 16;
    float* y_gt = (float*)((char*)ws + WS_SYNC_BYTES);  // [NCL][128][16] y exchange (transposed)
    float* h1t  = y_gt + NCL * D_ * RC;                 // [NCL][512][16]
    float* h2t  = h1t + NCL * F_ * RC;                  // [NCL][512][16]
    float* ygl = y_gt + cl * (D_ * RC);
    float* h1l = h1t + cl * (F_ * RC);
    float* h2l = h2t + cl * (F_ * RC);

    float* yfin  = out;
    float* ys_o  = out + B_ * D_;
    float* mup_o = ys_o  + (size_t)B_ * T_ * D_;
    float* mus_o = mup_o + (size_t)B_ * T_ * D_;
    float* std_o = mus_o + (size_t)B_ * T_ * D_;

    // ---- load weight slices to LDS (once) ----
    for (int e = tid; e < IN1 * 32; e += 256) { int k = e >> 5, c = e & 31; W1s[k * PW + c] = W1[k * F_ + cb + c]; }
    for (int e = tid; e < F_ * 32; e += 256)  { int k = e >> 5, c = e & 31; W2s[k * PW + c] = W2[k * F_ + cb + c]; }
    for (int e = tid; e < F_ * 8; e += 256)   { int k = e >> 3, c = e & 7;  W3s[k * PW3 + c] = W3[k * D_ + c3b + c]; }
    if (tid < 32) { b1s[tid] = b1[cb + tid]; b2s[tid] = b2[cb + tid]; }
    if (tid < 8)  { b3s[tid] = b3[c3b + tid]; }

    const int tile = tid & 7;
    const int ksg  = tid >> 3;
    const int r0   = (tile & 1) * 8;

    // pointwise thread's carried state: same (r,c) element every step
    float y_reg = 0.f;
    if (tid < 128) {
        int r = tid >> 3, c = tid & 7;
        y_reg = carry[(rb + r) * D_ + (c3b + c)];
    }

    unsigned g = 0;
    for (int t = 0; t < T_; t++) {
        // ---- prefetch pointwise inputs for this step (latency hides under the GEMMs) ----
        float x1p = 0.f, x2p = 0.f, nvp = 0.f;
        if (tid < 128) {
            int r = tid >> 3, c = tid & 7;
            size_t bt = (size_t)(rb + r) * T_ + t;
            x1p = x[bt * (2 * D_) + (c3b + c)];
            x2p = x[bt * (2 * D_) + D_ + (c3b + c)];
            nvp = noise[bt * D_ + (c3b + c)];
        }

        // ---- stage Z: act_t[k][r] = concat(y_{t-1}, u_t) transposed ----
        if (t == 0) {
            for (int e = tid; e < D_ * RC; e += 256) {
                int k = e >> 4, r = e & 15;
                act_t[k * PA + r] = carry[(rb + r) * D_ + k];
            }
        } else {
            // y exchange buffer is already transposed [k][r]; coherent-point pair loads
#pragma unroll
            for (int i = 0; i < 4; i++) {
                int e2 = tid * 2 + i * 512;
                int k = e2 >> 4, r = e2 & 15;
                float2 v = ld_coh2(ygl + e2);
                *(float2*)(act_t + k * PA + r) = v;
            }
        }
        for (int e = tid; e < E_ * RC; e += 256) {
            int u = e >> 4, r = e & 15;
            act_t[(D_ + u) * PA + r] = ext[((size_t)(rb + r) * T_ + t) * E_ + u];
        }
        __syncthreads();

        // ---- stage 1: h1 slice ----
        gemm_block<5>(act_t, W1s, b1s, act_t, h1l + cb * 16, tid);
        cluster_barrier(cnt, gen, ++g);

        // ---- restage full h1 (transposed, coherent-point loads) ----
#pragma unroll
        for (int i = 0; i < 8; i++) {
            int e4 = tid * 4 + i * 1024;
            float2 v0 = ld_coh2(h1l + e4);
            float2 v1 = ld_coh2(h1l + e4 + 2);
            int k = e4 >> 4, r = e4 & 15;
            *(float2*)(act_t + k * PA + r)     = v0;
            *(float2*)(act_t + k * PA + r + 2) = v1;
        }
        __syncthreads();

        // ---- stage 2: h2 slice ----
        gemm_block<16>(act_t, W2s, b2s, act_t, h2l + cb * 16, tid);
        cluster_barrier(cnt, gen, ++g);

        // ---- restage full h2 ----
#pragma unroll
        for (int i = 0; i < 8; i++) {
            int e4 = tid * 4 + i * 1024;
            float2 v0 = ld_coh2(h2l + e4);
            float2 v1 = ld_coh2(h2l + e4 + 2);
            int k = e4 >> 4, r = e4 & 15;
            *(float2*)(act_t + k * PA + r)     = v0;
            *(float2*)(act_t + k * PA + r + 2) = v1;
        }
        __syncthreads();

        // ---- stage 3: mu_phi slice [16 x 8] + pointwise ----
        {
            float2 acc2[8];
#pragma unroll
            for (int i = 0; i < 8; i++) acc2[i] = float2{0.f, 0.f};
            const float* ap = act_t + ksg * PA;
            const float* wp = W3s + ksg * PW3 + (tile >> 1) * 2;
#pragma unroll
            for (int kk = 0; kk < 16; kk++) {
                float4 a0 = *(const float4*)(ap + r0);
                float4 a1 = *(const float4*)(ap + r0 + 4);
                float2 w  = *(const float2*)wp;
                float av[8] = {a0.x, a0.y, a0.z, a0.w, a1.x, a1.y, a1.z, a1.w};
#pragma unroll
                for (int ri = 0; ri < 8; ri++) {
                    acc2[ri].x += av[ri] * w.x;
                    acc2[ri].y += av[ri] * w.y;
                }
                ap += 32 * PA; wp += 32 * PW3;
            }
            float* red = act_t;
            for (int half = 16; half >= 2; half >>= 1) {
                __syncthreads();
                if (ksg >= half && ksg < 2 * half) {
                    float2* d2 = (float2*)(red + (((ksg - half) << 3) + tile) * RST3);
#pragma unroll
                    for (int i = 0; i < 8; i++) d2[i] = acc2[i];
                }
                __syncthreads();
                if (ksg < half) {
                    const float2* s2 = (const float2*)(red + ((ksg << 3) + tile) * RST3);
#pragma unroll
                    for (int i = 0; i < 8; i++) { float2 u = s2[i]; acc2[i].x += u.x; acc2[i].y += u.y; }
                }
            }
            __syncthreads();
            if (ksg < 2) {
                float2* d2 = (float2*)(red + ((ksg << 3) + tile) * RST3);
#pragma unroll
                for (int i = 0; i < 8; i++) d2[i] = acc2[i];
            }
            __syncthreads();
            if (tid < 128) {
                int o = tid;
                int r = o >> 3, c = o & 7;
                int tl  = ((c >> 1) << 1) | (r >> 3);
                int idx = (r & 7) * 2 + (c & 1);
                float mu_phi = red[tl * RST3 + idx] + red[(8 + tl) * RST3 + idx] + b3s[c];
                int rg = rb + r;
                int cg = c3b + c;
                size_t bt = (size_t)rg * T_ + t;
                float mu = (1.0f - ALPHA_F) * y_reg + ALPHA_F * mu_phi + x1p;
                float sp = (x2p > 0.f) ? (x2p + log1pf(expf(-x2p))) : log1pf(expf(x2p));
                float sd = SCALE_F * sp;
                float yn = mu + sd * nvp;
                mup_o[bt * D_ + cg] = mu_phi;
                mus_o[bt * D_ + cg] = mu;
                std_o[bt * D_ + cg] = sd;
                ys_o [bt * D_ + cg] = yn;
                st_coh1(ygl + cg * 16 + r, yn);    // y exchange for next step's staging
                y_reg = yn;
                if (t == T_ - 1) yfin[rg * D_ + cg] = yn;
            }
        }
        cluster_barrier(cnt, gen, ++g);
    }
}

extern "C" void kernel_launch(void* const* d_in, const int* in_sizes, int n_in,
                              void* d_out, int out_size, void* d_ws, size_t ws_size,
                              hipStream_t stream) {
    const float* carry = (const float*)d_in[0];
    const float* x     = (const float*)d_in[1];
    const float* ext   = (const float*)d_in[2];
    const float* noise = (const float*)d_in[3];
    const float* W1    = (const float*)d_in[4];
    const float* b1    = (const float*)d_in[5];
    const float* W2    = (const float*)d_in[6];
    const float* b2    = (const float*)d_in[7];
    const float* W3    = (const float*)d_in[8];
    const float* b3    = (const float*)d_in[9];
    float* out = (float*)d_out;
    void* ws   = d_ws;

    // Only the sync counters need zeroing (exchange buffers are written-before-read).
    hipMemsetAsync(d_ws, 0, WS_SYNC_BYTES, stream);

    // Plain launch: grid = 256 = CU count, 1 block/CU by LDS usage -> co-resident.
    sde_scan_kernel<<<dim3(256), dim3(256), 0, stream>>>(
        carry, x, ext, noise, W1, b1, W2, b2, W3, b3, out, ws);
}

// Round 5
// 2568.793 us; speedup vs baseline: 11.4486x; 1.6831x over previous
//
#include <hip/hip_runtime.h>
#include <cmath>

// Problem constants: B=256, T=256, D=128, E=32, F1=F2=512
#define B_   256
#define T_   256
#define D_   128
#define E_   32
#define F_   512
#define CB   16             // blocks per cluster
#define RC   16             // rows per cluster
#define NCL  16             // clusters
#define ALPHA_F 0.1f
#define SCALE_F 0.31622776601683794f   // sqrt(0.1)
#define WS_SYNC_BYTES 4096

typedef float f32x4 __attribute__((ext_vector_type(4)));
typedef short s16x8 __attribute__((ext_vector_type(8)));
#define MFMA __builtin_amdgcn_mfma_f32_16x16x32_bf16

// ---- bf16 helpers (RNE) ----
__device__ __forceinline__ unsigned short f2bf(float f) {
    unsigned u = __float_as_uint(f);
    return (unsigned short)((u + 0x7FFFu + ((u >> 16) & 1u)) >> 16);
}
__device__ __forceinline__ unsigned pack2(float lo, float hi) {
    return (unsigned)f2bf(lo) | ((unsigned)f2bf(hi) << 16);
}

// ---- coherent-point primitives (sc0 sc1: write-through / L1-L2-bypass loads) ----
__device__ __forceinline__ void st_coh_u32(unsigned* p, unsigned v) {
    __hip_atomic_store(p, v, __ATOMIC_RELAXED, __HIP_MEMORY_SCOPE_AGENT);
}
__device__ __forceinline__ unsigned long long ld_coh_u64(const unsigned long long* p) {
    return __hip_atomic_load(p, __ATOMIC_RELAXED, __HIP_MEMORY_SCOPE_AGENT);
}

// A-fragment (short8 = 8 bf16) from frag exchange buffer; lane l expects
// elems (row = l&15, k = 32*s + 8*(l>>4) + [0..8)). Buffer layout: u32 index
// (s*64 + lane')*4 + piece, lane' = r + 16*((k>>3)&3), piece = (k&7)>>1.
__device__ __forceinline__ s16x8 ld_frag(const unsigned* fb, int s, int l) {
    union { unsigned long long q[2]; s16x8 v; } u;
    const unsigned long long* p = (const unsigned long long*)(fb + (unsigned)(s * 64 + l) * 4u);
    u.q[0] = ld_coh_u64(p);
    u.q[1] = ld_coh_u64(p + 1);
    return u.v;
}

// A-fragment from 8 consecutive f32 in global memory (carry / ext paths)
__device__ __forceinline__ s16x8 frag_from_f32(const float* p) {
    float4 a = *(const float4*)p;
    float4 b = *(const float4*)(p + 4);
    union { unsigned q[4]; s16x8 v; } u;
    u.q[0] = pack2(a.x, a.y); u.q[1] = pack2(a.z, a.w);
    u.q[2] = pack2(b.x, b.y); u.q[3] = pack2(b.z, b.w);
    return u.v;
}

// ---- cluster barrier (monotonic counter; proven in R3/R4) ----
__device__ __forceinline__ void cluster_barrier(unsigned* cnt, unsigned* gen, unsigned g) {
    asm volatile("s_waitcnt vmcnt(0)" ::: "memory");
    __syncthreads();
    if (threadIdx.x == 0) {
        unsigned a = __hip_atomic_fetch_add(cnt, 1u, __ATOMIC_RELAXED, __HIP_MEMORY_SCOPE_AGENT);
        if (a == g * CB - 1u) {
            __hip_atomic_store(gen, g, __ATOMIC_RELAXED, __HIP_MEMORY_SCOPE_AGENT);
        } else {
            while (__hip_atomic_load(gen, __ATOMIC_RELAXED, __HIP_MEMORY_SCOPE_AGENT) < g) {
                __builtin_amdgcn_s_sleep(1);
            }
        }
    }
    __syncthreads();
}

__global__ void __launch_bounds__(256, 1)
sde_scan_kernel(const float* __restrict__ carry, const float* __restrict__ x,
                const float* __restrict__ ext,   const float* __restrict__ noise,
                const float* __restrict__ W1,    const float* __restrict__ b1,
                const float* __restrict__ W2,    const float* __restrict__ b2,
                const float* __restrict__ W3,    const float* __restrict__ b3,
                float* __restrict__ out,         void* __restrict__ ws) {
    // bf16 weight fragments, converted once. B-frag: lane l = (c&15) + 16*((k>>3)&3), elem = k&7.
    __shared__ short W1f[2 * 5 * 64 * 8];    // 10 KB  (col-groups g=2, ksteps s=5)
    __shared__ short W2f[2 * 16 * 64 * 8];   // 32 KB
    __shared__ short W3f[16 * 64 * 8];       // 16 KB  (blocks j<8 only; cols 16j..16j+16)
    __shared__ float redb[8 * 64 * 4];       // 8 KB   (wave K-split combine)
    __shared__ float b1s[32], b2s[32], b3s[16];

    const int tid = threadIdx.x;
    const int bid = blockIdx.x;
    const int cl  = bid & 15;            // cluster (blocks cl, cl+16, ... -> same XCD under %8 rr)
    const int jb  = bid >> 4;            // block-in-cluster 0..15
    const int rb  = cl * RC;             // global batch-row base
    const int cb  = jb * 32;             // F1/F2 col base

    const int w  = tid >> 6;             // wave 0..3
    const int l  = tid & 63;             // lane
    const int lr = l & 15;               // frag row (batch row) / output col
    const int lh = l >> 4;               // k-octet / row-quad

    unsigned* syncb = (unsigned*)ws;
    unsigned* cnt = syncb + cl * 64;
    unsigned* gen = syncb + cl * 64 + 16;
    unsigned* yf  = (unsigned*)((char*)ws + WS_SYNC_BYTES) + cl * 1024;                  // 4 KB/cluster
    unsigned* h1f = (unsigned*)((char*)ws + WS_SYNC_BYTES + 65536) + cl * 4096;          // 16 KB/cluster
    unsigned* h2f = (unsigned*)((char*)ws + WS_SYNC_BYTES + 65536 + 262144) + cl * 4096; // 16 KB/cluster

    float* yfin  = out;
    float* ys_o  = out + B_ * D_;
    float* mup_o = ys_o  + (size_t)B_ * T_ * D_;
    float* mus_o = mup_o + (size_t)B_ * T_ * D_;
    float* std_o = mus_o + (size_t)B_ * T_ * D_;

    // ---- one-time weight conversion f32 -> bf16 frag layout ----
    for (int e4 = tid; e4 < 160 * 8; e4 += 256) {
        int k = e4 >> 3, c0 = (e4 & 7) << 2;
        float4 v = *(const float4*)(W1 + k * F_ + cb + c0);
        float vv[4] = {v.x, v.y, v.z, v.w};
#pragma unroll
        for (int m = 0; m < 4; m++) {
            int c = c0 + m;
            W1f[((((c >> 4) * 5 + (k >> 5)) * 64) + (c & 15) + 16 * ((k >> 3) & 3)) * 8 + (k & 7)] =
                (short)f2bf(vv[m]);
        }
    }
    for (int e4 = tid; e4 < 512 * 8; e4 += 256) {
        int k = e4 >> 3, c0 = (e4 & 7) << 2;
        float4 v = *(const float4*)(W2 + k * F_ + cb + c0);
        float vv[4] = {v.x, v.y, v.z, v.w};
#pragma unroll
        for (int m = 0; m < 4; m++) {
            int c = c0 + m;
            W2f[((((c >> 4) * 16 + (k >> 5)) * 64) + (c & 15) + 16 * ((k >> 3) & 3)) * 8 + (k & 7)] =
                (short)f2bf(vv[m]);
        }
    }
    if (jb < 8) {
        for (int e4 = tid; e4 < 512 * 4; e4 += 256) {
            int k = e4 >> 2, c0 = (e4 & 3) << 2;
            float4 v = *(const float4*)(W3 + k * D_ + 16 * jb + c0);
            float vv[4] = {v.x, v.y, v.z, v.w};
#pragma unroll
            for (int m = 0; m < 4; m++) {
                int c = c0 + m;
                W3f[(((k >> 5) * 64) + c + 16 * ((k >> 3) & 3)) * 8 + (k & 7)] = (short)f2bf(vv[m]);
            }
        }
    }
    if (tid < 32) { b1s[tid] = b1[cb + tid]; b2s[tid] = b2[cb + tid]; }
    if (tid < 16) { b3s[tid] = (jb < 8) ? b3[16 * jb + tid] : 0.f; }
    __syncthreads();

    // pointwise state (wave 0 of blocks jb<8): 4 rows (4*lh+i) x col cg3
    const int cg3 = 16 * jb + lr;
    float y_reg[4] = {0.f, 0.f, 0.f, 0.f};
    if (jb < 8 && w == 0) {
#pragma unroll
        for (int i = 0; i < 4; i++) y_reg[i] = carry[(size_t)(rb + 4 * lh + i) * D_ + cg3];
    }

    const f32x4 z4 = {0.f, 0.f, 0.f, 0.f};
    unsigned gbar = 0;

    for (int t = 0; t < T_; t++) {
        // prefetch pointwise inputs (hide under GEMMs)
        float x1p[4], x2p[4], nvp[4];
        if (jb < 8 && w == 0) {
#pragma unroll
            for (int i = 0; i < 4; i++) {
                size_t bt = (size_t)(rb + 4 * lh + i) * T_ + t;
                x1p[i] = x[bt * (2 * D_) + cg3];
                x2p[i] = x[bt * (2 * D_) + D_ + cg3];
                nvp[i] = noise[bt * D_ + cg3];
            }
        }

        // ================= GEMM1: z(160) -> h1 cols [32jb..32jb+32) =================
        // K-split: w0: s{0,1}, w1: s{2,3}, w2: s{4}=ext, w3 idle. Both col-groups per wave.
        if (w < 3) {
            f32x4 acc0 = z4, acc1 = z4;
            if (w == 2) {
                s16x8 a0 = frag_from_f32(ext + ((size_t)(rb + lr) * T_ + t) * E_ + 8 * lh);
                s16x8 b0 = *(const s16x8*)&W1f[((0 * 5 + 4) * 64 + l) * 8];
                s16x8 b1 = *(const s16x8*)&W1f[((1 * 5 + 4) * 64 + l) * 8];
                acc0 = MFMA(a0, b0, acc0, 0, 0, 0);
                acc1 = MFMA(a0, b1, acc1, 0, 0, 0);
            } else {
                int s0 = 2 * w, s1 = 2 * w + 1;
                s16x8 a0, a1;
                if (t == 0) {
                    a0 = frag_from_f32(carry + (size_t)(rb + lr) * D_ + 32 * s0 + 8 * lh);
                    a1 = frag_from_f32(carry + (size_t)(rb + lr) * D_ + 32 * s1 + 8 * lh);
                } else {
                    a0 = ld_frag(yf, s0, l);
                    a1 = ld_frag(yf, s1, l);
                }
                s16x8 b00 = *(const s16x8*)&W1f[((0 * 5 + s0) * 64 + l) * 8];
                s16x8 b01 = *(const s16x8*)&W1f[((0 * 5 + s1) * 64 + l) * 8];
                s16x8 b10 = *(const s16x8*)&W1f[((1 * 5 + s0) * 64 + l) * 8];
                s16x8 b11 = *(const s16x8*)&W1f[((1 * 5 + s1) * 64 + l) * 8];
                acc0 = MFMA(a0, b00, acc0, 0, 0, 0);
                acc0 = MFMA(a1, b01, acc0, 0, 0, 0);
                acc1 = MFMA(a0, b10, acc1, 0, 0, 0);
                acc1 = MFMA(a1, b11, acc1, 0, 0, 0);
            }
            *(f32x4*)&redb[((w * 2 + 0) * 64 + l) * 4] = acc0;
            *(f32x4*)&redb[((w * 2 + 1) * 64 + l) * 4] = acc1;
        }
        __syncthreads();
        if (w < 2) {   // wave w combines col-group g=w, applies bias+tanh, packs frags
            f32x4 s = *(const f32x4*)&redb[((0 * 2 + w) * 64 + l) * 4];
            f32x4 s1 = *(const f32x4*)&redb[((1 * 2 + w) * 64 + l) * 4];
            f32x4 s2 = *(const f32x4*)&redb[((2 * 2 + w) * 64 + l) * 4];
            int cl_ = 16 * w + lr;
            float bb = b1s[cl_];
#pragma unroll
            for (int i = 0; i < 4; i++) {
                float v = tanhf(s[i] + s1[i] + s2[i] + bb);
                float pv = __shfl_xor(v, 1);
                if (!(l & 1)) {
                    unsigned addr = (unsigned)(jb * 64 + 4 * lh + i + 16 * (cl_ >> 3)) * 4 + ((cl_ & 7) >> 1);
                    st_coh_u32(h1f + addr, pack2(v, pv));
                }
            }
        }
        cluster_barrier(cnt, gen, ++gbar);

        // ================= GEMM2: h1(512) -> h2 cols [32jb..32jb+32) =================
        {
            s16x8 af[4];
#pragma unroll
            for (int q = 0; q < 4; q++) af[q] = ld_frag(h1f, 4 * w + q, l);
            f32x4 acc0 = z4, acc1 = z4;
#pragma unroll
            for (int q = 0; q < 4; q++) {
                int s = 4 * w + q;
                s16x8 b0 = *(const s16x8*)&W2f[((0 * 16 + s) * 64 + l) * 8];
                s16x8 b1 = *(const s16x8*)&W2f[((1 * 16 + s) * 64 + l) * 8];
                acc0 = MFMA(af[q], b0, acc0, 0, 0, 0);
                acc1 = MFMA(af[q], b1, acc1, 0, 0, 0);
            }
            *(f32x4*)&redb[((w * 2 + 0) * 64 + l) * 4] = acc0;
            *(f32x4*)&redb[((w * 2 + 1) * 64 + l) * 4] = acc1;
        }
        __syncthreads();
        if (w < 2) {
            f32x4 s0 = *(const f32x4*)&redb[((0 * 2 + w) * 64 + l) * 4];
            f32x4 s1 = *(const f32x4*)&redb[((1 * 2 + w) * 64 + l) * 4];
            f32x4 s2 = *(const f32x4*)&redb[((2 * 2 + w) * 64 + l) * 4];
            f32x4 s3 = *(const f32x4*)&redb[((3 * 2 + w) * 64 + l) * 4];
            int cl_ = 16 * w + lr;
            float bb = b2s[cl_];
#pragma unroll
            for (int i = 0; i < 4; i++) {
                float v = tanhf(s0[i] + s1[i] + s2[i] + s3[i] + bb);
                float pv = __shfl_xor(v, 1);
                if (!(l & 1)) {
                    unsigned addr = (unsigned)(jb * 64 + 4 * lh + i + 16 * (cl_ >> 3)) * 4 + ((cl_ & 7) >> 1);
                    st_coh_u32(h2f + addr, pack2(v, pv));
                }
            }
        }
        cluster_barrier(cnt, gen, ++gbar);

        // ========== GEMM3: h2(512) -> mu_phi cols [16jb..16jb+16)  (blocks jb<8) ==========
        if (jb < 8) {
            s16x8 af[4];
#pragma unroll
            for (int q = 0; q < 4; q++) af[q] = ld_frag(h2f, 4 * w + q, l);
            f32x4 acc = z4;
#pragma unroll
            for (int q = 0; q < 4; q++) {
                s16x8 b0 = *(const s16x8*)&W3f[((4 * w + q) * 64 + l) * 8];
                acc = MFMA(af[q], b0, acc, 0, 0, 0);
            }
            if (w != 0) *(f32x4*)&redb[(w * 64 + l) * 4] = acc;
            __syncthreads();
            if (w == 0) {
                f32x4 p1 = *(const f32x4*)&redb[(1 * 64 + l) * 4];
                f32x4 p2 = *(const f32x4*)&redb[(2 * 64 + l) * 4];
                f32x4 p3 = *(const f32x4*)&redb[(3 * 64 + l) * 4];
                float bb = b3s[lr];
                float yn4[4];
#pragma unroll
                for (int i = 0; i < 4; i++) {
                    float mu_phi = acc[i] + p1[i] + p2[i] + p3[i] + bb;
                    int rg = rb + 4 * lh + i;
                    size_t bt = (size_t)rg * T_ + t;
                    float mu = (1.0f - ALPHA_F) * y_reg[i] + ALPHA_F * mu_phi + x1p[i];
                    float sp = (x2p[i] > 0.f) ? (x2p[i] + log1pf(expf(-x2p[i]))) : log1pf(expf(x2p[i]));
                    float sd = SCALE_F * sp;
                    float yn = mu + sd * nvp[i];
                    mup_o[bt * D_ + cg3] = mu_phi;
                    mus_o[bt * D_ + cg3] = mu;
                    std_o[bt * D_ + cg3] = sd;
                    ys_o [bt * D_ + cg3] = yn;
                    y_reg[i] = yn;
                    yn4[i] = yn;
                    if (t == T_ - 1) yfin[(size_t)rg * D_ + cg3] = yn;
                }
                // y-frag exchange for next step's GEMM1 (k = 16*jb + lr)
#pragma unroll
                for (int i = 0; i < 4; i++) {
                    float pv = __shfl_xor(yn4[i], 1);
                    if (!(l & 1)) {
                        int k = 16 * jb + lr;   // even
                        unsigned addr = (unsigned)((k >> 5) * 64 + 4 * lh + i + 16 * ((k >> 3) & 3)) * 4
                                        + ((lr & 7) >> 1);
                        st_coh_u32(yf + addr, pack2(yn4[i], pv));
                    }
                }
            }
        }
        cluster_barrier(cnt, gen, ++gbar);
    }
}

extern "C" void kernel_launch(void* const* d_in, const int* in_sizes, int n_in,
                              void* d_out, int out_size, void* d_ws, size_t ws_size,
                              hipStream_t stream) {
    const float* carry = (const float*)d_in[0];
    const float* x     = (const float*)d_in[1];
    const float* ext   = (const float*)d_in[2];
    const float* noise = (const float*)d_in[3];
    const float* W1    = (const float*)d_in[4];
    const float* b1    = (const float*)d_in[5];
    const float* W2    = (const float*)d_in[6];
    const float* b2    = (const float*)d_in[7];
    const float* W3    = (const float*)d_in[8];
    const float* b3    = (const float*)d_in[9];
    float* out = (float*)d_out;
    void* ws   = d_ws;

    // Only sync counters need zeroing (frag buffers are fully overwritten before read).
    hipMemsetAsync(d_ws, 0, WS_SYNC_BYTES, stream);

    sde_scan_kernel<<<dim3(256), dim3(256), 0, stream>>>(
        carry, x, ext, noise, W1, b1, W2, b2, W3, b3, out, ws);
}